// Round 1
// baseline (46.445 us; speedup 1.0000x reference)
//
#include <hip/hip_runtime.h>

// Geometry fixed by setup_inputs(): B=8, C=3, h_patches=w_patches=64, P=16,
// h_padding=w_padding=8 -> output (8,3,1016,1016) fp32.
constexpr int PATCH  = 16;
constexpr int HP     = 64;        // h_patches
constexpr int WP     = 64;        // w_patches
constexpr int NPATCH = HP * WP;   // 4096
constexpr int OH     = HP * PATCH - 8;   // 1016
constexpr int OW     = WP * PATCH - 8;   // 1016
constexpr int OW4    = OW / 4;           // 254 float4 per row

__global__ __launch_bounds__(256)
void recons_kernel(const float* __restrict__ in, float* __restrict__ out) {
    const int t  = threadIdx.x;          // float4 column index within row
    if (t >= OW4) return;                // 254 of 256 lanes active
    const int h  = blockIdx.x;           // output row   [0, 1016)
    const int bc = blockIdx.y;           // fused (b, c) [0, 24)

    const int w  = t << 2;               // output col (multiple of 4)
    const int pr = h >> 4;               // patch row
    const int ph = h & 15;               // row within patch
    const int pc = w >> 4;               // patch col
    const int pw = w & 15;               // col within patch (0,4,8,12)

    // input flat index: ((bc*NPATCH + pr*WP + pc)*16 + ph)*16 + pw
    const long long n      = (long long)bc * NPATCH + pr * WP + pc;
    const long long in_off = ((n << 4) + ph) * 16 + pw;

    const long long out_off = (((long long)bc * OH + h) * OW4 + t) << 2;

    const float4 v = *reinterpret_cast<const float4*>(in + in_off);
    *reinterpret_cast<float4*>(out + out_off) = v;
}

extern "C" void kernel_launch(void* const* d_in, const int* in_sizes, int n_in,
                              void* d_out, int out_size, void* d_ws, size_t ws_size,
                              hipStream_t stream) {
    const float* in = (const float*)d_in[0];
    float* out = (float*)d_out;
    dim3 grid(OH, 8 * 3);   // (rows, B*C)
    dim3 block(256);
    recons_kernel<<<grid, block, 0, stream>>>(in, out);
}

// Round 2
// 34.645 us; speedup vs baseline: 1.3406x; 1.3406x over previous
//
#include <hip/hip_runtime.h>

// Geometry fixed by setup_inputs(): B=8, C=3, h_patches=w_patches=64, P=16,
// h_padding=w_padding=8 -> output (8,3,1016,1016) fp32.
constexpr int PATCH  = 16;
constexpr int HP     = 64;        // h_patches
constexpr int WP     = 64;        // w_patches
constexpr int NPATCH = HP * WP;   // 4096
constexpr int OH     = HP * PATCH - 8;   // 1016
constexpr int OW     = WP * PATCH - 8;   // 1016
constexpr int OW4    = OW / 4;           // 254 float4 per row
constexpr int RPT    = 4;                // rows per thread
constexpr int NG     = OH / RPT;         // 254 row-groups

__global__ __launch_bounds__(256)
void recons_kernel(const float* __restrict__ in, float* __restrict__ out) {
    const int t = threadIdx.x;           // float4 column index within row
    if (t >= OW4) return;                // 254 of 256 lanes active
    const int g  = blockIdx.x;           // row group [0, 254): rows 4g..4g+3
    const int bc = blockIdx.y;           // fused (b, c) [0, 24)

    const int h0  = g << 2;              // first output row of group
    const int pr  = g >> 2;              // patch row   (4 groups per patch)
    const int ph0 = (g & 3) << 2;        // first row within patch (0,4,8,12)
    const int w   = t << 2;              // output col (multiple of 4)
    const int pc  = w >> 4;              // patch col
    const int pw  = w & 15;              // col within patch (0,4,8,12)

    // patch base: (bc*NPATCH + pr*WP + pc) * 256 floats
    const long long n = (long long)bc * NPATCH + pr * WP + pc;
    const float* __restrict__ src = in + (n << 8) + ph0 * PATCH + pw;
    float* __restrict__ dst = out + ((long long)bc * OH + h0) * OW + w;

    // 4-lane group (same patch) covers 256 B contiguous input across the
    // 4 row iterations; writes are per-row contiguous across the wave.
    const float4 v0 = *reinterpret_cast<const float4*>(src);
    const float4 v1 = *reinterpret_cast<const float4*>(src + PATCH);
    const float4 v2 = *reinterpret_cast<const float4*>(src + 2 * PATCH);
    const float4 v3 = *reinterpret_cast<const float4*>(src + 3 * PATCH);

    *reinterpret_cast<float4*>(dst)          = v0;
    *reinterpret_cast<float4*>(dst + OW)     = v1;
    *reinterpret_cast<float4*>(dst + 2 * OW) = v2;
    *reinterpret_cast<float4*>(dst + 3 * OW) = v3;
}

extern "C" void kernel_launch(void* const* d_in, const int* in_sizes, int n_in,
                              void* d_out, int out_size, void* d_ws, size_t ws_size,
                              hipStream_t stream) {
    const float* in = (const float*)d_in[0];
    float* out = (float*)d_out;
    dim3 grid(NG, 8 * 3);   // (row-groups, B*C)
    dim3 block(256);
    recons_kernel<<<grid, block, 0, stream>>>(in, out);
}